// Round 21
// baseline (281.068 us; speedup 1.0000x reference)
//
#include <hip/hip_runtime.h>
#include <math.h>

typedef unsigned short u16;
typedef __attribute__((ext_vector_type(8))) short s8v;   // 8 x bf16 (4 VGPRs)
typedef __attribute__((ext_vector_type(4))) float f4v;   // MFMA accumulator

#define NUM_CLASSES 91
#define NUM_ANCHORS 9
#define NT2 247            // total 16x4 spatial tiles across 5 levels
#define TG8 31             // ceil(NT2/8)
#define TW_STRIDE (256*256*9)
#define PSTRIDE 872        // padded LDS part stride (u16): bank offset 20
#define GC (8 * 4 * TG8)   // cls cohort grid: 992

struct Tab {
    int tstart[5];  // first tile index per level
    int tw[5];      // tiles along W
    int H[5], W[5], GP0[5];
};

__device__ __forceinline__ u16 f2bf(float f) {
    unsigned u = __float_as_uint(f);
    u += 0x7fffu + ((u >> 16) & 1u);
    return (u16)(u >> 16);
}

// ---------------------------------------------------------------------------
// Pack conv weights [C_out][256][3][3] fp32 -> bf16 MFMA B-fragment order,
// CO16-MAJOR: slot = co16*72 + chunk, chunk = tap*8 + cib32.
// ---------------------------------------------------------------------------
__device__ __forceinline__ void pack_one(const float* __restrict__ w,
                                         u16* __restrict__ dst,
                                         int idx, int c_out_real)
{
    int lane = idx & 63;
    int t2 = idx >> 6;
    int chunk = t2 % 72;
    int co16 = t2 / 72;
    int tap = chunk >> 3, cib = chunk & 7;
    int co = co16 * 16 + (lane & 15);
    int ci0 = cib * 32 + ((lane >> 4) << 3);
    s8v v8;
    #pragma unroll
    for (int j = 0; j < 8; ++j) {
        float v = (co < c_out_real) ? w[((co << 8) + ci0 + j) * 9 + tap] : 0.f;
        v8[j] = (short)f2bf(v);
    }
    *(s8v*)(dst + (size_t)idx * 8) = v8;
}

#define PACK_TOTAL (8 * 72 * 16 * 64 + 72 * 52 * 64 + 72 * 3 * 64)  // 843264
#define PACK_BLKS  ((PACK_TOTAL + 255) / 256)                        // 3294
#define CONV_BLKS  ((13343 + 63) / 64)                               // 209

// ---------------------------------------------------------------------------
// prep_all: one launch = all weight packing (blocks [0, PACK_BLKS)) +
// fp32 NCHW -> bf16 [pixel][256] activation convert (remaining blocks).
// ---------------------------------------------------------------------------
__global__ __launch_bounds__(256) void prep_all(
    const float* __restrict__ cls_tw, const float* __restrict__ reg_tw,
    const float* __restrict__ cls_ow, const float* __restrict__ reg_ow,
    u16* __restrict__ pt, size_t pt_stride_u16,
    u16* __restrict__ pc, u16* __restrict__ pr,
    const float* __restrict__ f0, const float* __restrict__ f1,
    const float* __restrict__ f2, const float* __restrict__ f3,
    const float* __restrict__ f4, u16* __restrict__ act, Tab tab)
{
    const int bid = blockIdx.x;
    if (bid < PACK_BLKS) {
        int idx = bid * 256 + threadIdx.x;
        const int per_t = 72 * 16 * 64;           // 73728
        const int cls_n = 72 * 52 * 64;           // 239616
        if (idx < 8 * per_t) {
            int layer = idx / per_t;
            int r = idx - layer * per_t;
            const float* src = (layer < 4) ? cls_tw + (size_t)layer * TW_STRIDE
                                           : reg_tw + (size_t)(layer - 4) * TW_STRIDE;
            pack_one(src, pt + (size_t)layer * pt_stride_u16, r, 256);
        } else if (idx < 8 * per_t + cls_n) {
            pack_one(cls_ow, pc, idx - 8 * per_t, 819);
        } else if (idx < PACK_TOTAL) {
            pack_one(reg_ow, pr, idx - 8 * per_t - cls_n, 36);
        }
    } else {
        int gp = (bid - PACK_BLKS) * 64 + (threadIdx.x & 63);
        int cg = threadIdx.x >> 6;              // 0..3
        if (gp >= 13343) return;
        int lvl = 0;
        if (gp >= tab.GP0[1]) lvl = 1;
        if (gp >= tab.GP0[2]) lvl = 2;
        if (gp >= tab.GP0[3]) lvl = 3;
        if (gp >= tab.GP0[4]) lvl = 4;
        const float* x = lvl == 0 ? f0 : lvl == 1 ? f1 : lvl == 2 ? f2
                       : lvl == 3 ? f3 : f4;
        int p = gp - tab.GP0[lvl];
        int HW = tab.H[lvl] * tab.W[lvl];
        #pragma unroll
        for (int pass = 0; pass < 8; ++pass) {
            int c0 = pass * 32 + cg * 8;
            s8v v8;
            #pragma unroll
            for (int j = 0; j < 8; ++j)
                v8[j] = (short)f2bf(x[(c0 + j) * HW + p]);
            *(s8v*)(act + (((size_t)gp << 8) + c0)) = v8;
        }
    }
}

// fallback per-table pack + standalone convert (small-ws path)
__global__ __launch_bounds__(256) void pack_w(const float* __restrict__ w,
                                              u16* __restrict__ dst,
                                              int c_out_real, int nco16)
{
    int idx = blockIdx.x * 256 + threadIdx.x;
    if (idx < 72 * nco16 * 64) pack_one(w, dst, idx, c_out_real);
}

__global__ __launch_bounds__(256) void conv2bf_all(
    const float* __restrict__ f0, const float* __restrict__ f1,
    const float* __restrict__ f2, const float* __restrict__ f3,
    const float* __restrict__ f4, u16* __restrict__ out, Tab tab)
{
    int gp = blockIdx.x * 64 + (threadIdx.x & 63);
    int cg = threadIdx.x >> 6;
    if (gp >= 13343) return;
    int lvl = 0;
    if (gp >= tab.GP0[1]) lvl = 1;
    if (gp >= tab.GP0[2]) lvl = 2;
    if (gp >= tab.GP0[3]) lvl = 3;
    if (gp >= tab.GP0[4]) lvl = 4;
    const float* x = lvl == 0 ? f0 : lvl == 1 ? f1 : lvl == 2 ? f2 : lvl == 3 ? f3 : f4;
    int p = gp - tab.GP0[lvl];
    int HW = tab.H[lvl] * tab.W[lvl];
    #pragma unroll
    for (int pass = 0; pass < 8; ++pass) {
        int c0 = pass * 32 + cg * 8;
        s8v v8;
        #pragma unroll
        for (int j = 0; j < 8; ++j)
            v8[j] = (short)f2bf(x[(c0 + j) * HW + p]);
        *(s8v*)(out + (((size_t)gp << 8) + c0)) = v8;
    }
}

// ---------------------------------------------------------------------------
// Chunked-LDS implicit-GEMM conv core. NTHR/64 waves share one 64-px
// (16w x 4h) tile; waves split co (co16w = bx*(NW*ACCN)+wv*ACCN).
// 128-ci chunks (2 total): LDS [part16][108px][8u16] (part stride 872 ->
// conflict floor), 3 barriers/kernel. Inner (cib32 = cib*4+cs, kx, ky) order
// identical to the 64-ci version -> bitwise-identical results.
// kx-outer A-dedup. B co16-major.
// MODE: 0 tower / 1 cls (sigmoid scatter) / 2 reg + FUSED box decode.
// ---------------------------------------------------------------------------
template<int MODE, int NCO16, int ACCN, int NTHR>
__device__ __forceinline__ void conv_core(
    u16* __restrict__ lds,
    const u16* __restrict__ act, const u16* __restrict__ wpk,
    const float* __restrict__ bias,
    u16* __restrict__ outw, float* __restrict__ fout,
    int bx, int by, const Tab& tab)
{
    constexpr int NW = NTHR / 64;                  // waves per block
    constexpr int SJOBS = (1728 + NTHR - 1) / NTHR;

    int lvl = 0;
    if (by >= tab.tstart[1]) lvl = 1;
    if (by >= tab.tstart[2]) lvl = 2;
    if (by >= tab.tstart[3]) lvl = 3;
    if (by >= tab.tstart[4]) lvl = 4;
    const int H = tab.H[lvl], W = tab.W[lvl], gp0 = tab.GP0[lvl];
    const int t = by - tab.tstart[lvl];
    const int tw = tab.tw[lvl];
    const int w0 = (t % tw) * 16;
    const int h0 = (t / tw) * 4;

    const int tid = threadIdx.x;
    const int lane = tid & 63, wv = tid >> 6;
    const int co16w = bx * (NW * ACCN) + wv * ACCN;   // wave's first co16
    const int kg = lane >> 4;                         // ci sub-group 0..3
    const int col = lane & 15;

    // staging jobs: 1728 x 16B lane-loads (108 px x 16 parts) per 128-ci chunk
    int sofs[SJOBS], slds[SJOBS];
    bool svalid[SJOBS], slive[SJOBS];
    #pragma unroll
    for (int i = 0; i < SJOBS; ++i) {
        int k = tid + i * NTHR;
        slive[i] = k < 1728;
        int kk = slive[i] ? k : 0;
        int px = kk >> 4, part = kk & 15;
        int hh = px / 18, ww = px - hh * 18;
        int gh = h0 + hh - 1, gw = w0 + ww - 1;
        svalid[i] = ((unsigned)gh < (unsigned)H) && ((unsigned)gw < (unsigned)W);
        sofs[i] = ((gp0 + gh * W + gw) << 8) + part * 8;
        slds[i] = part * PSTRIDE + px * 8;
    }

    // per-wave B base pointers (clamped co16); co16-major: co16 stride 72*512
    const u16* bbn[ACCN];
    #pragma unroll
    for (int n = 0; n < ACCN; ++n) {
        int c = co16w + n;
        if (c >= NCO16) c = NCO16 - 1;
        bbn[n] = wpk + ((size_t)(c * 72) << 9) + (lane << 3);
    }

    f4v acc[4][ACCN];
    #pragma unroll
    for (int s = 0; s < 4; ++s)
        #pragma unroll
        for (int n = 0; n < ACCN; ++n)
            acc[s][n] = (f4v){0.f, 0.f, 0.f, 0.f};

    s8v pre[SJOBS];     // in-flight stage loads (one 128-ci chunk)
    auto ISSUE_S = [&](int cc) {
        #pragma unroll
        for (int i = 0; i < SJOBS; ++i) {
            s8v v = {};
            if (slive[i] && svalid[i])
                v = *(const s8v*)(act + sofs[i] + cc * 128);
            pre[i] = v;
        }
    };

    ISSUE_S(0);
    #pragma unroll 1
    for (int cib = 0; cib < 2; ++cib) {
        if (cib) __syncthreads();      // all waves done reading prev chunk
        #pragma unroll
        for (int i = 0; i < SJOBS; ++i)
            if (slive[i]) *(s8v*)(&lds[slds[i]]) = pre[i];
        __syncthreads();

        #pragma unroll
        for (int cs = 0; cs < 4; ++cs) {
            const u16* L = &lds[(cs * 4 + kg) * PSTRIDE];
            #pragma unroll
            for (int kx = 0; kx < 3; ++kx) {
                s8v a[6];
                #pragma unroll
                for (int r = 0; r < 6; ++r)
                    a[r] = *(const s8v*)(&L[(r * 18 + col + kx) * 8]);
                #pragma unroll
                for (int ky = 0; ky < 3; ++ky) {
                    s8v b[ACCN];
                    #pragma unroll
                    for (int n = 0; n < ACCN; ++n)
                        b[n] = *(const s8v*)(bbn[n] +
                            ((size_t)((ky * 3 + kx) * 8 + cib * 4 + cs) << 9));
                    #pragma unroll
                    for (int s = 0; s < 4; ++s)
                        #pragma unroll
                        for (int n = 0; n < ACCN; ++n)
                            acc[s][n] = __builtin_amdgcn_mfma_f32_16x16x32_bf16(
                                a[s + ky], b[n], acc[s][n], 0, 0, 0);
                }
                if (cs == 0 && kx == 0 && cib < 1) ISSUE_S(cib + 1);
            }
        }
    }

    // ---- epilogue: D col = lane&15 -> co; D row = (lane>>4)*4+j -> px ----
    if (MODE == 2) {
        // reg: stage raw [64px][40 f32] in LDS, then fused box decode
        float* Rf = (float*)lds;
        __syncthreads();                   // compute LDS no longer needed
        #pragma unroll
        for (int n = 0; n < ACCN; ++n) {
            const int co = (co16w + n) * 16 + col;
            if (co < 36) {
                const float bval = bias[co];
                #pragma unroll
                for (int s = 0; s < 4; ++s)
                    #pragma unroll
                    for (int j = 0; j < 4; ++j) {
                        int px = (s << 4) + ((lane >> 4) << 2) + j;
                        Rf[px * 40 + co] = acc[s][n][j] + bval;
                    }
            }
        }
        __syncthreads();
        const float stridef = (float)(8 << lvl);
        const float basef = (float)(32 << lvl);
        const float scales[3] = {1.f, 1.2599210498948732f, 1.5874010519681994f};
        const float hrt[3] = {0.70710678118654752f, 1.f, 1.41421356237309505f};
        const float CLAMP = 4.135166556742356f;
        for (int job = tid; job < 576; job += NTHR) {
            int px = job / 9, a = job - (job / 9) * 9;
            int r = px >> 4, c = px & 15;
            int gh = h0 + r, gw = w0 + c;
            if (gh < H && gw < W) {
                f4v d = *(const f4v*)(&Rf[px * 40 + a * 4]);
                int ri = a / 3, si = a - ri * 3;
                float sz = basef * scales[si];
                float ah = hrt[ri] * sz;
                float aw = sz / hrt[ri];
                float acx = (float)gw * stridef;
                float acy = (float)gh * stridef;
                float dw = fminf(d[2], CLAMP);
                float dh = fminf(d[3], CLAMP);
                float pcx = d[0] * aw + acx;
                float pcy = d[1] * ah + acy;
                float pw = expf(dw) * aw;
                float ph = expf(dh) * ah;
                float* o = fout + ((size_t)(gp0 + gh * W + gw) * 9 + a) * 95 + 91;
                o[0] = pcx - 0.5f * pw;
                o[1] = pcy - 0.5f * ph;
                o[2] = pcx + 0.5f * pw;
                o[3] = pcy + 0.5f * ph;
            }
        }
        return;
    }
    #pragma unroll
    for (int n = 0; n < ACCN; ++n) {
        const int co = (co16w + n) * 16 + (lane & 15);   // real, unclamped
        if (co < NCO16 * 16) {
            #pragma unroll
            for (int s = 0; s < 4; ++s) {
                const int h = h0 + s;
                #pragma unroll
                for (int j = 0; j < 4; ++j) {
                    const int w = w0 + ((lane >> 4) << 2) + j;
                    if (h < H && w < W) {
                        const int p = h * W + w;
                        if (MODE == 0) {
                            float v = acc[s][n][j] + bias[co];
                            outw[((size_t)(gp0 + p) << 8) + co] = f2bf(fmaxf(v, 0.f));
                        } else {
                            if (co < NUM_ANCHORS * NUM_CLASSES) {
                                float v = acc[s][n][j] + bias[co];
                                int a = co / NUM_CLASSES;
                                int k = co - a * NUM_CLASSES;
                                float sg = 1.f / (1.f + __expf(-v));
                                fout[((size_t)(gp0 + p) * 9 + a) * 95 + k] = sg;
                            }
                        }
                    }
                }
            }
        }
    }
}

// ---------------------------------------------------------------------------
// XCD-cohort swizzled wrappers: dispatch slot s -> XCD s%8 (round-robin).
// ---------------------------------------------------------------------------

// towers: 512 thr, full 256-co in ONE pass; slot = xcd + 8*(head + 2*tg)
__global__ __launch_bounds__(512, 4) void conv_tower(
    const u16* __restrict__ actC, u16* __restrict__ outC,
    const u16* __restrict__ actR, u16* __restrict__ outR,
    const u16* __restrict__ wC, const u16* __restrict__ wR,
    const float* __restrict__ bC, const float* __restrict__ bR, Tab tab)
{
    __shared__ u16 lds[16 * PSTRIDE];
    const int s = blockIdx.x;
    const int xcd = s & 7;
    const int q = s >> 3;
    const int head = q & 1;
    const int t = (q >> 1) * 8 + xcd;
    if (t >= NT2) return;
    conv_core<0, 16, 2, 512>(lds, head ? actR : actC, head ? wR : wC,
                             head ? bR : bC, head ? outR : outC, nullptr,
                             0, t, tab);
}

// outputs: blocks [0,GC) = cls (cohort mapping, 16 co16/block, 4 passes);
// blocks [GC, GC+NT2) = reg with fused box decode (fills cls tail).
__global__ __launch_bounds__(512, 4) void conv_out(
    const u16* __restrict__ actD, const u16* __restrict__ actA,
    const u16* __restrict__ wPC, const u16* __restrict__ wPR,
    const float* __restrict__ cls_ob, const float* __restrict__ reg_ob,
    float* __restrict__ out, Tab tab)
{
    __shared__ u16 lds[16 * PSTRIDE];
    const int s = blockIdx.x;
    if (s < GC) {
        const int xcd = s & 7;
        const int q = s >> 3;
        const int pass = q & 3;
        const int t = (q >> 2) * 8 + xcd;
        if (t >= NT2) return;
        conv_core<1, 52, 2, 512>(lds, actD, wPC, cls_ob, nullptr, out,
                                 pass, t, tab);
    } else {
        conv_core<2, 3, 1, 512>(lds, actA, wPR, reg_ob, nullptr, out,
                                0, s - GC, tab);
    }
}

// ---------------------------------------------------------------------------
extern "C" void kernel_launch(void* const* d_in, const int* in_sizes, int n_in,
                              void* d_out, int out_size, void* d_ws, size_t ws_size,
                              hipStream_t stream)
{
    const float* f0 = (const float*)d_in[0];
    const float* f1 = (const float*)d_in[1];
    const float* f2 = (const float*)d_in[2];
    const float* f3 = (const float*)d_in[3];
    const float* f4 = (const float*)d_in[4];
    const float* cls_tw = (const float*)d_in[5];
    const float* cls_tb = (const float*)d_in[6];
    const float* cls_ow = (const float*)d_in[7];
    const float* cls_ob = (const float*)d_in[8];
    const float* reg_tw = (const float*)d_in[9];
    const float* reg_tb = (const float*)d_in[10];
    const float* reg_ow = (const float*)d_in[11];
    const float* reg_ob = (const float*)d_in[12];
    float* out = (float*)d_out;

    static const Tab TAB = {
        {0, 175, 227, 241, 245},
        {7, 4, 2, 1, 1},
        {100, 50, 25, 13, 7},
        {100, 50, 25, 13, 7},
        {0, 10000, 12500, 13125, 13294}
    };

    char* wsb = (char*)d_ws;
    const size_t AS = 6832128;                 // act buffer stride (bytes)
    u16* A = (u16*)(wsb + 0 * AS);
    u16* B = (u16*)(wsb + 1 * AS);
    u16* C = (u16*)(wsb + 2 * AS);
    u16* D = (u16*)(wsb + 3 * AS);

    const u16* cin[4]   = {A, B, D, B};
    u16*       cout_[4] = {B, D, B, D};
    const u16* rin[4]   = {A, C, A, C};
    u16*       rout[4]  = {C, A, C, A};

    const size_t PTSZ = 1179648;               // one packed tower layer (bytes)
    const bool big = ws_size >= (4 * AS + 8 * PTSZ + 3833856 + 221184);

    const int GT = 8 * 2 * TG8;                // tower grid: 496 (512-thr)
    const int GO = GC + NT2;                   // output grid: 1239 (512-thr)

    if (big) {
        u16* PT = (u16*)(wsb + 4 * AS);
        u16* PC = (u16*)(wsb + 4 * AS + 8 * PTSZ);
        u16* PR = (u16*)(wsb + 4 * AS + 8 * PTSZ + 3833856);

        // 1+2) weight packing + activation convert, one launch
        prep_all<<<PACK_BLKS + CONV_BLKS, 256, 0, stream>>>(
            cls_tw, reg_tw, cls_ow, reg_ow, PT, PTSZ / 2, PC, PR,
            f0, f1, f2, f3, f4, A, TAB);

        // 3) towers: 512-thr single-co-pass, XCD-cohort swizzled, both heads
        for (int s = 0; s < 4; ++s)
            conv_tower<<<GT, 512, 0, stream>>>(
                cin[s], cout_[s], rin[s], rout[s],
                PT + (size_t)s * (PTSZ / 2), PT + (size_t)(4 + s) * (PTSZ / 2),
                cls_tb + s * 256, reg_tb + s * 256, TAB);

        // 4) cls + reg(+decode) fused output launch
        conv_out<<<GO, 512, 0, stream>>>(D, A, PC, PR, cls_ob, reg_ob, out, TAB);
    } else {
        u16* PC = (u16*)(wsb + 4 * AS);
        u16* PR = (u16*)(wsb + 4 * AS + 3833856);
        conv2bf_all<<<CONV_BLKS, 256, 0, stream>>>(f0, f1, f2, f3, f4, A, TAB);
        for (int s = 0; s < 4; ++s) {
            pack_w<<<(72 * 16 * 64 + 255) / 256, 256, 0, stream>>>(cls_tw + s * TW_STRIDE, PC, 256, 16);
            pack_w<<<(72 * 16 * 64 + 255) / 256, 256, 0, stream>>>(reg_tw + s * TW_STRIDE, PR, 256, 16);
            conv_tower<<<GT, 512, 0, stream>>>(
                cin[s], cout_[s], rin[s], rout[s], PC, PR,
                cls_tb + s * 256, reg_tb + s * 256, TAB);
        }
        pack_w<<<(72 * 52 * 64 + 255) / 256, 256, 0, stream>>>(cls_ow, PC, 819, 52);
        pack_w<<<(72 * 3 * 64 + 255) / 256, 256, 0, stream>>>(reg_ow, PR, 36, 3);
        conv_out<<<GO, 512, 0, stream>>>(D, A, PC, PR, cls_ob, reg_ob, out, TAB);
    }
}

// Round 22
// 278.385 us; speedup vs baseline: 1.0096x; 1.0096x over previous
//
#include <hip/hip_runtime.h>
#include <math.h>

typedef unsigned short u16;
typedef __attribute__((ext_vector_type(8))) short s8v;   // 8 x bf16 (4 VGPRs)
typedef __attribute__((ext_vector_type(4))) float f4v;   // MFMA accumulator

#define NUM_CLASSES 91
#define NUM_ANCHORS 9
#define NT2 247            // total 16x4 spatial tiles across 5 levels
#define TG8 31             // ceil(NT2/8)
#define TW_STRIDE (256*256*9)
#define PSTRIDE 872        // padded LDS part stride (u16): bank offset 20
#define GC (8 * 4 * TG8)   // cls cohort grid: 992

struct Tab {
    int tstart[5];  // first tile index per level
    int tw[5];      // tiles along W
    int H[5], W[5], GP0[5];
};

__device__ __forceinline__ u16 f2bf(float f) {
    unsigned u = __float_as_uint(f);
    u += 0x7fffu + ((u >> 16) & 1u);
    return (u16)(u >> 16);
}

// ---------------------------------------------------------------------------
// Pack conv weights [C_out][256][3][3] fp32 -> bf16 MFMA B-fragment order,
// CO16-MAJOR: slot = co16*72 + chunk, chunk = tap*8 + cib32.
// ---------------------------------------------------------------------------
__device__ __forceinline__ void pack_one(const float* __restrict__ w,
                                         u16* __restrict__ dst,
                                         int idx, int c_out_real)
{
    int lane = idx & 63;
    int t2 = idx >> 6;
    int chunk = t2 % 72;
    int co16 = t2 / 72;
    int tap = chunk >> 3, cib = chunk & 7;
    int co = co16 * 16 + (lane & 15);
    int ci0 = cib * 32 + ((lane >> 4) << 3);
    s8v v8;
    #pragma unroll
    for (int j = 0; j < 8; ++j) {
        float v = (co < c_out_real) ? w[((co << 8) + ci0 + j) * 9 + tap] : 0.f;
        v8[j] = (short)f2bf(v);
    }
    *(s8v*)(dst + (size_t)idx * 8) = v8;
}

#define PACK_TOTAL (8 * 72 * 16 * 64 + 72 * 52 * 64 + 72 * 3 * 64)  // 843264
#define PACK_BLKS  ((PACK_TOTAL + 255) / 256)                        // 3294
#define CONV_BLKS  ((13343 + 63) / 64)                               // 209

// ---------------------------------------------------------------------------
// prep_all: one launch = all weight packing (blocks [0, PACK_BLKS)) +
// fp32 NCHW -> bf16 [pixel][256] activation convert (remaining blocks).
// ---------------------------------------------------------------------------
__global__ __launch_bounds__(256) void prep_all(
    const float* __restrict__ cls_tw, const float* __restrict__ reg_tw,
    const float* __restrict__ cls_ow, const float* __restrict__ reg_ow,
    u16* __restrict__ pt, size_t pt_stride_u16,
    u16* __restrict__ pc, u16* __restrict__ pr,
    const float* __restrict__ f0, const float* __restrict__ f1,
    const float* __restrict__ f2, const float* __restrict__ f3,
    const float* __restrict__ f4, u16* __restrict__ act, Tab tab)
{
    const int bid = blockIdx.x;
    if (bid < PACK_BLKS) {
        int idx = bid * 256 + threadIdx.x;
        const int per_t = 72 * 16 * 64;           // 73728
        const int cls_n = 72 * 52 * 64;           // 239616
        if (idx < 8 * per_t) {
            int layer = idx / per_t;
            int r = idx - layer * per_t;
            const float* src = (layer < 4) ? cls_tw + (size_t)layer * TW_STRIDE
                                           : reg_tw + (size_t)(layer - 4) * TW_STRIDE;
            pack_one(src, pt + (size_t)layer * pt_stride_u16, r, 256);
        } else if (idx < 8 * per_t + cls_n) {
            pack_one(cls_ow, pc, idx - 8 * per_t, 819);
        } else if (idx < PACK_TOTAL) {
            pack_one(reg_ow, pr, idx - 8 * per_t - cls_n, 36);
        }
    } else {
        int gp = (bid - PACK_BLKS) * 64 + (threadIdx.x & 63);
        int cg = threadIdx.x >> 6;              // 0..3
        if (gp >= 13343) return;
        int lvl = 0;
        if (gp >= tab.GP0[1]) lvl = 1;
        if (gp >= tab.GP0[2]) lvl = 2;
        if (gp >= tab.GP0[3]) lvl = 3;
        if (gp >= tab.GP0[4]) lvl = 4;
        const float* x = lvl == 0 ? f0 : lvl == 1 ? f1 : lvl == 2 ? f2
                       : lvl == 3 ? f3 : f4;
        int p = gp - tab.GP0[lvl];
        int HW = tab.H[lvl] * tab.W[lvl];
        #pragma unroll
        for (int pass = 0; pass < 8; ++pass) {
            int c0 = pass * 32 + cg * 8;
            s8v v8;
            #pragma unroll
            for (int j = 0; j < 8; ++j)
                v8[j] = (short)f2bf(x[(c0 + j) * HW + p]);
            *(s8v*)(act + (((size_t)gp << 8) + c0)) = v8;
        }
    }
}

// fallback per-table pack + standalone convert (small-ws path)
__global__ __launch_bounds__(256) void pack_w(const float* __restrict__ w,
                                              u16* __restrict__ dst,
                                              int c_out_real, int nco16)
{
    int idx = blockIdx.x * 256 + threadIdx.x;
    if (idx < 72 * nco16 * 64) pack_one(w, dst, idx, c_out_real);
}

__global__ __launch_bounds__(256) void conv2bf_all(
    const float* __restrict__ f0, const float* __restrict__ f1,
    const float* __restrict__ f2, const float* __restrict__ f3,
    const float* __restrict__ f4, u16* __restrict__ out, Tab tab)
{
    int gp = blockIdx.x * 64 + (threadIdx.x & 63);
    int cg = threadIdx.x >> 6;
    if (gp >= 13343) return;
    int lvl = 0;
    if (gp >= tab.GP0[1]) lvl = 1;
    if (gp >= tab.GP0[2]) lvl = 2;
    if (gp >= tab.GP0[3]) lvl = 3;
    if (gp >= tab.GP0[4]) lvl = 4;
    const float* x = lvl == 0 ? f0 : lvl == 1 ? f1 : lvl == 2 ? f2 : lvl == 3 ? f3 : f4;
    int p = gp - tab.GP0[lvl];
    int HW = tab.H[lvl] * tab.W[lvl];
    #pragma unroll
    for (int pass = 0; pass < 8; ++pass) {
        int c0 = pass * 32 + cg * 8;
        s8v v8;
        #pragma unroll
        for (int j = 0; j < 8; ++j)
            v8[j] = (short)f2bf(x[(c0 + j) * HW + p]);
        *(s8v*)(out + (((size_t)gp << 8) + c0)) = v8;
    }
}

// ---------------------------------------------------------------------------
// Chunked-LDS implicit-GEMM conv core (R12-proven). NTHR/64 waves share one
// 64-px (16w x 4h) tile; waves split co (co16w = bx*(NW*ACCN)+wv*ACCN).
// 64-ci chunks in LDS [part8][108px][8u16] (part stride 872 -> conflict
// floor). kx-outer A-dedup. B co16-major.
// MODE: 0 tower / 1 cls (sigmoid scatter) / 2 reg + FUSED box decode.
// ---------------------------------------------------------------------------
template<int MODE, int NCO16, int ACCN, int NTHR>
__device__ __forceinline__ void conv_core(
    u16* __restrict__ lds,
    const u16* __restrict__ act, const u16* __restrict__ wpk,
    const float* __restrict__ bias,
    u16* __restrict__ outw, float* __restrict__ fout,
    int bx, int by, const Tab& tab)
{
    constexpr int NW = NTHR / 64;                 // waves per block
    constexpr int SJOBS = (864 + NTHR - 1) / NTHR;

    int lvl = 0;
    if (by >= tab.tstart[1]) lvl = 1;
    if (by >= tab.tstart[2]) lvl = 2;
    if (by >= tab.tstart[3]) lvl = 3;
    if (by >= tab.tstart[4]) lvl = 4;
    const int H = tab.H[lvl], W = tab.W[lvl], gp0 = tab.GP0[lvl];
    const int t = by - tab.tstart[lvl];
    const int tw = tab.tw[lvl];
    const int w0 = (t % tw) * 16;
    const int h0 = (t / tw) * 4;

    const int tid = threadIdx.x;
    const int lane = tid & 63, wv = tid >> 6;
    const int co16w = bx * (NW * ACCN) + wv * ACCN;   // wave's first co16
    const int kg = lane >> 4;                         // ci sub-group 0..3
    const int col = lane & 15;

    // staging jobs: 864 x 16B lane-loads (108 px x 8 parts)
    int sofs[SJOBS], slds[SJOBS];
    bool svalid[SJOBS], slive[SJOBS];
    #pragma unroll
    for (int i = 0; i < SJOBS; ++i) {
        int k = tid + i * NTHR;
        slive[i] = k < 864;
        int kk = slive[i] ? k : 0;
        int px = kk >> 3, part = kk & 7;
        int hh = px / 18, ww = px - hh * 18;
        int gh = h0 + hh - 1, gw = w0 + ww - 1;
        svalid[i] = ((unsigned)gh < (unsigned)H) && ((unsigned)gw < (unsigned)W);
        sofs[i] = ((gp0 + gh * W + gw) << 8) + part * 8;
        slds[i] = part * PSTRIDE + px * 8;
    }

    // per-wave B base pointers (clamped co16); co16-major: co16 stride 72*512
    const u16* bbn[ACCN];
    #pragma unroll
    for (int n = 0; n < ACCN; ++n) {
        int c = co16w + n;
        if (c >= NCO16) c = NCO16 - 1;
        bbn[n] = wpk + ((size_t)(c * 72) << 9) + (lane << 3);
    }

    f4v acc[4][ACCN];
    #pragma unroll
    for (int s = 0; s < 4; ++s)
        #pragma unroll
        for (int n = 0; n < ACCN; ++n)
            acc[s][n] = (f4v){0.f, 0.f, 0.f, 0.f};

    s8v pre[SJOBS];     // in-flight stage loads (one 64-ci chunk)
    auto ISSUE_S = [&](int cc) {
        #pragma unroll
        for (int i = 0; i < SJOBS; ++i) {
            s8v v = {};
            if (slive[i] && svalid[i])
                v = *(const s8v*)(act + sofs[i] + cc * 64);
            pre[i] = v;
        }
    };

    ISSUE_S(0);
    #pragma unroll 1
    for (int cib = 0; cib < 4; ++cib) {
        if (cib) __syncthreads();      // all waves done reading prev chunk
        #pragma unroll
        for (int i = 0; i < SJOBS; ++i)
            if (slive[i]) *(s8v*)(&lds[slds[i]]) = pre[i];
        __syncthreads();

        #pragma unroll
        for (int cs = 0; cs < 2; ++cs) {
            const u16* L = &lds[(cs * 4 + kg) * PSTRIDE];
            #pragma unroll
            for (int kx = 0; kx < 3; ++kx) {
                s8v a[6];
                #pragma unroll
                for (int r = 0; r < 6; ++r)
                    a[r] = *(const s8v*)(&L[(r * 18 + col + kx) * 8]);
                #pragma unroll
                for (int ky = 0; ky < 3; ++ky) {
                    s8v b[ACCN];
                    #pragma unroll
                    for (int n = 0; n < ACCN; ++n)
                        b[n] = *(const s8v*)(bbn[n] +
                            ((size_t)((ky * 3 + kx) * 8 + cib * 2 + cs) << 9));
                    #pragma unroll
                    for (int s = 0; s < 4; ++s)
                        #pragma unroll
                        for (int n = 0; n < ACCN; ++n)
                            acc[s][n] = __builtin_amdgcn_mfma_f32_16x16x32_bf16(
                                a[s + ky], b[n], acc[s][n], 0, 0, 0);
                }
                if (cs == 0 && kx == 0 && cib < 3) ISSUE_S(cib + 1);
            }
        }
    }

    // ---- epilogue: D col = lane&15 -> co; D row = (lane>>4)*4+j -> px ----
    if (MODE == 2) {
        // reg: stage raw [64px][40 f32] in LDS, then fused box decode
        float* Rf = (float*)lds;
        __syncthreads();                   // compute LDS no longer needed
        #pragma unroll
        for (int n = 0; n < ACCN; ++n) {
            const int co = (co16w + n) * 16 + col;
            if (co < 36) {
                const float bval = bias[co];
                #pragma unroll
                for (int s = 0; s < 4; ++s)
                    #pragma unroll
                    for (int j = 0; j < 4; ++j) {
                        int px = (s << 4) + ((lane >> 4) << 2) + j;
                        Rf[px * 40 + co] = acc[s][n][j] + bval;
                    }
            }
        }
        __syncthreads();
        const float stridef = (float)(8 << lvl);
        const float basef = (float)(32 << lvl);
        const float scales[3] = {1.f, 1.2599210498948732f, 1.5874010519681994f};
        const float hrt[3] = {0.70710678118654752f, 1.f, 1.41421356237309505f};
        const float CLAMP = 4.135166556742356f;
        for (int job = tid; job < 576; job += NTHR) {
            int px = job / 9, a = job - (job / 9) * 9;
            int r = px >> 4, c = px & 15;
            int gh = h0 + r, gw = w0 + c;
            if (gh < H && gw < W) {
                f4v d = *(const f4v*)(&Rf[px * 40 + a * 4]);
                int ri = a / 3, si = a - ri * 3;
                float sz = basef * scales[si];
                float ah = hrt[ri] * sz;
                float aw = sz / hrt[ri];
                float acx = (float)gw * stridef;
                float acy = (float)gh * stridef;
                float dw = fminf(d[2], CLAMP);
                float dh = fminf(d[3], CLAMP);
                float pcx = d[0] * aw + acx;
                float pcy = d[1] * ah + acy;
                float pw = expf(dw) * aw;
                float ph = expf(dh) * ah;
                float* o = fout + ((size_t)(gp0 + gh * W + gw) * 9 + a) * 95 + 91;
                o[0] = pcx - 0.5f * pw;
                o[1] = pcy - 0.5f * ph;
                o[2] = pcx + 0.5f * pw;
                o[3] = pcy + 0.5f * ph;
            }
        }
        return;
    }
    #pragma unroll
    for (int n = 0; n < ACCN; ++n) {
        const int co = (co16w + n) * 16 + (lane & 15);   // real, unclamped
        if (co < NCO16 * 16) {
            #pragma unroll
            for (int s = 0; s < 4; ++s) {
                const int h = h0 + s;
                #pragma unroll
                for (int j = 0; j < 4; ++j) {
                    const int w = w0 + ((lane >> 4) << 2) + j;
                    if (h < H && w < W) {
                        const int p = h * W + w;
                        if (MODE == 0) {
                            float v = acc[s][n][j] + bias[co];
                            outw[((size_t)(gp0 + p) << 8) + co] = f2bf(fmaxf(v, 0.f));
                        } else {
                            if (co < NUM_ANCHORS * NUM_CLASSES) {
                                float v = acc[s][n][j] + bias[co];
                                int a = co / NUM_CLASSES;
                                int k = co - a * NUM_CLASSES;
                                float sg = 1.f / (1.f + __expf(-v));
                                fout[((size_t)(gp0 + p) * 9 + a) * 95 + k] = sg;
                            }
                        }
                    }
                }
            }
        }
    }
}

// ---------------------------------------------------------------------------
// XCD-cohort swizzled wrappers: dispatch slot s -> XCD s%8 (round-robin).
// ---------------------------------------------------------------------------

// towers: 512 thr, full 256-co in ONE pass; slot = xcd + 8*(head + 2*tg)
__global__ __launch_bounds__(512, 4) void conv_tower(
    const u16* __restrict__ actC, u16* __restrict__ outC,
    const u16* __restrict__ actR, u16* __restrict__ outR,
    const u16* __restrict__ wC, const u16* __restrict__ wR,
    const float* __restrict__ bC, const float* __restrict__ bR, Tab tab)
{
    __shared__ u16 lds[8 * PSTRIDE];
    const int s = blockIdx.x;
    const int xcd = s & 7;
    const int q = s >> 3;
    const int head = q & 1;
    const int t = (q >> 1) * 8 + xcd;
    if (t >= NT2) return;
    conv_core<0, 16, 2, 512>(lds, head ? actR : actC, head ? wR : wC,
                             head ? bR : bC, head ? outR : outC, nullptr,
                             0, t, tab);
}

// outputs: blocks [0,GC) = cls (R18 cohort mapping, 16 co16/block, 4 passes);
// blocks [GC, GC+NT2) = reg with fused box decode (fills cls tail).
__global__ __launch_bounds__(512, 4) void conv_out(
    const u16* __restrict__ actD, const u16* __restrict__ actA,
    const u16* __restrict__ wPC, const u16* __restrict__ wPR,
    const float* __restrict__ cls_ob, const float* __restrict__ reg_ob,
    float* __restrict__ out, Tab tab)
{
    __shared__ u16 lds[8 * PSTRIDE];
    const int s = blockIdx.x;
    if (s < GC) {
        const int xcd = s & 7;
        const int q = s >> 3;
        const int pass = q & 3;
        const int t = (q >> 2) * 8 + xcd;
        if (t >= NT2) return;
        conv_core<1, 52, 2, 512>(lds, actD, wPC, cls_ob, nullptr, out,
                                 pass, t, tab);
    } else {
        conv_core<2, 3, 1, 512>(lds, actA, wPR, reg_ob, nullptr, out,
                                0, s - GC, tab);
    }
}

// ---------------------------------------------------------------------------
extern "C" void kernel_launch(void* const* d_in, const int* in_sizes, int n_in,
                              void* d_out, int out_size, void* d_ws, size_t ws_size,
                              hipStream_t stream)
{
    const float* f0 = (const float*)d_in[0];
    const float* f1 = (const float*)d_in[1];
    const float* f2 = (const float*)d_in[2];
    const float* f3 = (const float*)d_in[3];
    const float* f4 = (const float*)d_in[4];
    const float* cls_tw = (const float*)d_in[5];
    const float* cls_tb = (const float*)d_in[6];
    const float* cls_ow = (const float*)d_in[7];
    const float* cls_ob = (const float*)d_in[8];
    const float* reg_tw = (const float*)d_in[9];
    const float* reg_tb = (const float*)d_in[10];
    const float* reg_ow = (const float*)d_in[11];
    const float* reg_ob = (const float*)d_in[12];
    float* out = (float*)d_out;

    static const Tab TAB = {
        {0, 175, 227, 241, 245},
        {7, 4, 2, 1, 1},
        {100, 50, 25, 13, 7},
        {100, 50, 25, 13, 7},
        {0, 10000, 12500, 13125, 13294}
    };

    char* wsb = (char*)d_ws;
    const size_t AS = 6832128;                 // act buffer stride (bytes)
    u16* A = (u16*)(wsb + 0 * AS);
    u16* B = (u16*)(wsb + 1 * AS);
    u16* C = (u16*)(wsb + 2 * AS);
    u16* D = (u16*)(wsb + 3 * AS);

    const u16* cin[4]   = {A, B, D, B};
    u16*       cout_[4] = {B, D, B, D};
    const u16* rin[4]   = {A, C, A, C};
    u16*       rout[4]  = {C, A, C, A};

    const size_t PTSZ = 1179648;               // one packed tower layer (bytes)
    const bool big = ws_size >= (4 * AS + 8 * PTSZ + 3833856 + 221184);

    const int GT = 8 * 2 * TG8;                // tower grid: 496 (512-thr)
    const int GO = GC + NT2;                   // output grid: 1239 (512-thr)

    if (big) {
        u16* PT = (u16*)(wsb + 4 * AS);
        u16* PC = (u16*)(wsb + 4 * AS + 8 * PTSZ);
        u16* PR = (u16*)(wsb + 4 * AS + 8 * PTSZ + 3833856);

        // 1+2) weight packing + activation convert, one launch
        prep_all<<<PACK_BLKS + CONV_BLKS, 256, 0, stream>>>(
            cls_tw, reg_tw, cls_ow, reg_ow, PT, PTSZ / 2, PC, PR,
            f0, f1, f2, f3, f4, A, TAB);

        // 3) towers: 512-thr single-co-pass, XCD-cohort swizzled, both heads
        for (int s = 0; s < 4; ++s)
            conv_tower<<<GT, 512, 0, stream>>>(
                cin[s], cout_[s], rin[s], rout[s],
                PT + (size_t)s * (PTSZ / 2), PT + (size_t)(4 + s) * (PTSZ / 2),
                cls_tb + s * 256, reg_tb + s * 256, TAB);

        // 4) cls + reg(+decode) fused output launch
        conv_out<<<GO, 512, 0, stream>>>(D, A, PC, PR, cls_ob, reg_ob, out, TAB);
    } else {
        u16* PC = (u16*)(wsb + 4 * AS);
        u16* PR = (u16*)(wsb + 4 * AS + 3833856);
        conv2bf_all<<<CONV_BLKS, 256, 0, stream>>>(f0, f1, f2, f3, f4, A, TAB);
        for (int s = 0; s < 4; ++s) {
            pack_w<<<(72 * 16 * 64 + 255) / 256, 256, 0, stream>>>(cls_tw + s * TW_STRIDE, PC, 256, 16);
            pack_w<<<(72 * 16 * 64 + 255) / 256, 256, 0, stream>>>(reg_tw + s * TW_STRIDE, PR, 256, 16);
            conv_tower<<<GT, 512, 0, stream>>>(
                cin[s], cout_[s], rin[s], rout[s], PC, PR,
                cls_tb + s * 256, reg_tb + s * 256, TAB);
        }
        pack_w<<<(72 * 52 * 64 + 255) / 256, 256, 0, stream>>>(cls_ow, PC, 819, 52);
        pack_w<<<(72 * 3 * 64 + 255) / 256, 256, 0, stream>>>(reg_ow, PR, 36, 3);
        conv_out<<<GO, 512, 0, stream>>>(D, A, PC, PR, cls_ob, reg_ob, out, TAB);
    }
}